// Round 15
// baseline (112.956 us; speedup 1.0000x reference)
//
#include <hip/hip_runtime.h>
#include <stdint.h>

typedef uint32_t u32;
typedef uint64_t u64;

#define NLVL 4
#define NPRE 2000
#define NPOST 1000
#define KPAD 8192
#define TIE_CAP 4096
#define NCHUNK 128          // chunk count (125 used, padded to 128)

// ws layout (bytes)
#define OFF_SBITS 0u                        // 1 MB  (250K u32)
#define OFF_CTRL  (2u<<20)                  // 4 KB  [k_zero]
#define OFF_H1    ((2u<<20) + (4u<<10))     // 4 KB  u32[4][256] exponent hist [k_zero]
#define OFF_HM    ((2u<<20) + (8u<<10))     // 4 KB  u32[4][256] mantissa hist [k_zero]
#define ZERO_WORDS 3072                     // 12 KB contiguous from OFF_CTRL
#define OFF_RANKP ((2u<<20) + (16u<<10))    // 256 KB u32[8][8192] partial ranks (no zeroing)
#define OFF_TIE   ((2u<<20) + (288u<<10))   // 128 KB u64[4][4096]
#define OFF_CAND  ((2u<<20) + (416u<<10))   // 64 KB u64[8192]  (unsorted)
#define OFF_SHIFT ((2u<<20) + (480u<<10))   // 128 KB float4[8192] (sorted order)
#define OFF_CAND2 ((2u<<20) + (608u<<10))   // 64 KB u64[8192]  (sorted)
#define OFF_KEPT  ((2u<<20) + (672u<<10))   // 4 KB  (fallback path only)
#define OFF_MASK  (3u<<20)                  // 8 MB: maskT2[128 row-chunks][8192 cols] u64
#define WS_NEED   ((size_t)(3u<<20) + (size_t)NCHUNK * KPAD * 8u)

// ctrl word indices -- each hot group on its OWN 64B cacheline
#define C_CANDCNT 0    // line 0: block-aggregated adds
#define C_KEPTCNT 1
#define C_SEPMAX  16   // line 1: wave-reduced atomicMax (k_rankp h==0 only)
#define C_P       32   // line 2: threshold (b>>15 value) + RANK (written by k_compact blk0)
#define C_RANK    36
#define C_TIECNT  48   // line 3: block-aggregated tie adds

// exact midpoint between 0.7f (0x3F333333) and nextafterf(0.7f) (0x3F333334):
// RN32(inter/den) > 0.7f  <=>  inter/den >= MID (ties round to even = 0x3F333334 > 0.7f).
// (double)inter and (double)den are exact; MID*(double)den needs <=49 bits -> exact.
#define MID 0x1.666667p-1

// ---- monotone float<->u32 map for atomic max over floats ----
__device__ __forceinline__ u32 fmap(float f) {
  u32 u = __float_as_uint(f);
  return (u & 0x80000000u) ? ~u : (u | 0x80000000u);
}
__device__ __forceinline__ float funmap(u32 u) {
  u = (u & 0x80000000u) ? (u & 0x7FFFFFFFu) : ~u;
  return __uint_as_float(u);
}

// ---- replicate XLA-CPU GenerateVF32Exp (Cephes/Eigen-3.3 style) ----
__device__ __forceinline__ float xla_expf(float x) {
  const float kLog2e = 1.44269504088896341f;
  const float kC1 = 0.693359375f;
  const float kC2 = -2.12194440e-4f;
  const float kP0 = 1.9875691500e-4f;
  const float kP1 = 1.3981999507e-3f;
  const float kP2 = 8.3334519073e-3f;
  const float kP3 = 4.1665795894e-2f;
  const float kP4 = 1.6666665459e-1f;
  const float kP5 = 5.0000001201e-1f;
  float xc = fminf(fmaxf(x, -88.3762626647949f), 88.3762626647950f);
  float fx = floorf(fmaf(xc, kLog2e, 0.5f));
  float tmp = __fmul_rn(kC1, fx);
  float z = __fmul_rn(kC2, fx);
  float r = __fsub_rn(xc, tmp);
  r = __fsub_rn(r, z);
  float r2 = __fmul_rn(r, r);
  float y = fmaf(r, kP0, kP1);
  y = fmaf(y, r, kP2);
  y = fmaf(y, r, kP3);
  y = fmaf(y, r, kP4);
  y = fmaf(y, r, kP5);
  y = fmaf(y, r2, r);
  y = __fadd_rn(y, 1.0f);
  int n = (int)fx;
  float two_n = __int_as_float((n + 127) << 23);
  return fmaxf(__fmul_rn(y, two_n), x);
}

// ---- IoU(a,b) > 0.7f, reference's exact f32 op sequence (fallback path) ----
__device__ __forceinline__ bool suppress(float4 a, float4 b) {
  float aa = __fmul_rn(__fsub_rn(a.z, a.x), __fsub_rn(a.w, a.y));
  float ab = __fmul_rn(__fsub_rn(b.z, b.x), __fsub_rn(b.w, b.y));
  float lty = fmaxf(a.x, b.x);
  float ltx = fmaxf(a.y, b.y);
  float rby = fminf(a.z, b.z);
  float rbx = fminf(a.w, b.w);
  float why = fmaxf(__fsub_rn(rby, lty), 0.0f);
  float whx = fmaxf(__fsub_rn(rbx, ltx), 0.0f);
  float inter = __fmul_rn(why, whx);
  float uni = __fsub_rn(__fadd_rn(aa, ab), inter);
  float iou = inter / fmaxf(uni, 1e-9f);
  return iou > 0.7f;
}

// ---- div-free IoU decision: provably identical to suppress() (see MID note) ----
__device__ __forceinline__ bool sup_fast(float ra, float4 r, float ca, float4 c) {
  float lty = fmaxf(r.x, c.x);
  float ltx = fmaxf(r.y, c.y);
  float rby = fminf(r.z, c.z);
  float rbx = fminf(r.w, c.w);
  float why = fmaxf(__fsub_rn(rby, lty), 0.0f);
  float whx = fmaxf(__fsub_rn(rbx, ltx), 0.0f);
  float inter = __fmul_rn(why, whx);
  float uni = __fsub_rn(__fadd_rn(ra, ca), inter);
  float den = fmaxf(uni, 1e-9f);
  return (double)inter >= MID * (double)den;
}

__device__ __forceinline__ u64 makekey(u32 sbits, u32 lvl, u32 idx) {
  // ascending key == (score desc, level asc, index asc); total order (idx unique)
  return ((u64)(0x7FFFFFFFu - sbits) << 20) | ((u64)lvl << 18) | (u64)idx;
}

// ---- wave-parallel descending rank-scan over a 256-bin histogram ----
__device__ __forceinline__ void rank_scan256(const u32* __restrict__ h, u32 target,
                                             int lane, u32* bin_out, u32* before_out) {
  u32 b0 = h[255 - 4 * lane];
  u32 b1 = h[254 - 4 * lane];
  u32 b2 = h[253 - 4 * lane];
  u32 b3 = h[252 - 4 * lane];
  u32 s = b0 + b1 + b2 + b3;
  u32 inc = s;
  for (int o = 1; o < 64; o <<= 1) {
    u32 v = (u32)__shfl_up((int)inc, o);
    if (lane >= o) inc += v;
  }
  u32 excl = inc - s;
  u32 tot = (u32)__shfl((int)inc, 63);
  if (tot < target) { *bin_out = 0xFFFFFFFFu; *before_out = 0u; return; }
  bool hit = (excl < target) && (excl + s >= target);
  u32 E = 0, before = 0;
  if (hit) {
    u32 cum = excl;
    if (cum + b0 >= target) { E = 255 - 4 * (u32)lane; before = cum; }
    else { cum += b0;
      if (cum + b1 >= target) { E = 254 - 4 * (u32)lane; before = cum; }
      else { cum += b1;
        if (cum + b2 >= target) { E = 253 - 4 * (u32)lane; before = cum; }
        else { cum += b2; E = 252 - 4 * (u32)lane; before = cum; }
      }
    }
  }
  u64 hb = __ballot(hit);
  int src = __ffsll((unsigned long long)hb) - 1;
  *bin_out = (u32)__shfl((int)E, src);
  *before_out = (u32)__shfl((int)before, src);
}

// 0) tiny zero kernel: ctrl + hist1 + histm (12KB) -- replaces hipMemsetAsync
__global__ __launch_bounds__(512) void k_zero(u32* __restrict__ p) {
  int i = blockIdx.x * 512 + threadIdx.x;
  if (i < ZERO_WORDS) p[i] = 0;
}

// 1) softmax score + LDS-aggregated exponent histogram (4KB global footprint)
__global__ __launch_bounds__(512) void k_score_hist(const float2* __restrict__ logits,
                                                    const int* __restrict__ levels,
                                                    u32* __restrict__ sbits,
                                                    u32* __restrict__ hist1, int n) {
  __shared__ u32 lh[NLVL * 256];
  int tid = threadIdx.x;
  for (int p = tid; p < NLVL * 256; p += 512) lh[p] = 0;
  __syncthreads();
  int i = blockIdx.x * 512 + tid;
  if (i < n) {
    float2 lg = logits[i];
    float m = fmaxf(lg.x, lg.y);
    float e0 = xla_expf(__fsub_rn(lg.x, m));
    float e1 = xla_expf(__fsub_rn(lg.y, m));
    float s = e1 / __fadd_rn(e0, e1);   // IEEE div
    u32 b = __float_as_uint(s);
    sbits[i] = b;
    int lv = levels[i];
    atomicAdd(&lh[lv * 256 + (int)((b >> 23) & 0xFFu)], 1u);
  }
  __syncthreads();
  for (int p = tid; p < NLVL * 256; p += 512) {
    u32 v = lh[p];
    if (v) atomicAdd(&hist1[p], v);
  }
}

// 2) mantissa histogram (bits 22:15) restricted to exp==E; E computed IN-BLOCK
__global__ __launch_bounds__(512) void k_hist_m(const u32* __restrict__ sbits,
                                                const int* __restrict__ levels,
                                                const u32* __restrict__ hist1,
                                                u32* __restrict__ histm, int n) {
  __shared__ u32 lh[NLVL * 256];
  __shared__ u32 sE[NLVL];
  int tid = threadIdx.x;
  int lane = tid & 63, w = tid >> 6;
  for (int p = tid; p < NLVL * 256; p += 512) lh[p] = 0;
  if (w < NLVL) {
    u32 E, bef;
    rank_scan256(hist1 + w * 256, NPRE, lane, &E, &bef);
    if (lane == 0) sE[w] = E;
  }
  __syncthreads();
  int i = blockIdx.x * 512 + tid;
  if (i < n) {
    u32 b = sbits[i];
    int lv = levels[i];
    if (((b >> 23) & 0xFFu) == sE[lv])
      atomicAdd(&lh[lv * 256 + (int)((b >> 15) & 0xFFu)], 1u);
  }
  __syncthreads();
  for (int p = tid; p < NLVL * 256; p += 512) {
    u32 v = lh[p];
    if (v) atomicAdd(&histm[p], v);
  }
}

// 3) compact with BLOCK-AGGREGATED atomics; threshold computed IN-BLOCK.
__global__ __launch_bounds__(512) void k_compact(const u32* __restrict__ sbits,
                                                 const int* __restrict__ levels,
                                                 const u32* __restrict__ hist1,
                                                 const u32* __restrict__ histm,
                                                 u32* __restrict__ ctrl,
                                                 u64* __restrict__ cand,
                                                 u64* __restrict__ tie, int n) {
  __shared__ u32 wcnt[8], wtieS[8][4];
  __shared__ u32 wbase, tiebase[4];
  __shared__ u32 sP[NLVL], sRANK[NLVL];
  int tid = threadIdx.x;
  int wid = tid >> 6, lane = tid & 63;
  if (wid < NLVL) {
    u32 E, bef1;
    rank_scan256(hist1 + wid * 256, NPRE, lane, &E, &bef1);
    u32 P = 0xFFFFFFFFu, RK = 0;
    if (E != 0xFFFFFFFFu) {
      u32 R1 = NPRE - bef1;          // elements needed inside exponent bin E
      u32 M, bef2;
      rank_scan256(histm + wid * 256, R1, lane, &M, &bef2);
      P = (E << 8) | M;
      RK = R1 - bef2;                // elements needed inside threshold bin
    }
    if (lane == 0) {
      sP[wid] = P; sRANK[wid] = RK;
      if (blockIdx.x == 0) { ctrl[C_P + wid] = P; ctrl[C_RANK + wid] = RK; }
    }
  }
  __syncthreads();
  int i = blockIdx.x * 512 + tid;
  bool act = i < n;
  u32 b = 0; int lv = 0; u32 P = 0xFFFFFFFEu;
  if (act) {
    b = sbits[i];
    lv = levels[i];
    P = sP[lv];
  }
  u32 K = b >> 15;
  bool iscand = act && (P == 0xFFFFFFFFu || K > P);
  bool istie  = act && !iscand && (K == P);
  u64 cb = __ballot(iscand);
  u64 t0 = __ballot(istie && lv == 0);
  u64 t1 = __ballot(istie && lv == 1);
  u64 t2 = __ballot(istie && lv == 2);
  u64 t3 = __ballot(istie && lv == 3);
  if (lane == 0) {
    wcnt[wid] = (u32)__popcll(cb);
    wtieS[wid][0] = (u32)__popcll(t0);
    wtieS[wid][1] = (u32)__popcll(t1);
    wtieS[wid][2] = (u32)__popcll(t2);
    wtieS[wid][3] = (u32)__popcll(t3);
  }
  __syncthreads();
  if (tid == 0) {
    u32 tot = 0;
#pragma unroll
    for (int w = 0; w < 8; ++w) tot += wcnt[w];
    wbase = tot ? atomicAdd(&ctrl[C_CANDCNT], tot) : 0u;
  }
  if (tid < 4) {
    u32 tt = 0;
#pragma unroll
    for (int w = 0; w < 8; ++w) tt += wtieS[w][tid];
    tiebase[tid] = tt ? atomicAdd(&ctrl[C_TIECNT + tid], tt) : 0u;
  }
  __syncthreads();
  u64 lm = (1ull << lane) - 1ull;
  if (iscand) {
    u32 pre = 0;
    for (int w = 0; w < wid; ++w) pre += wcnt[w];
    u32 pos = wbase + pre + (u32)__popcll(cb & lm);
    if (pos < (u32)KPAD) cand[pos] = makekey(b, (u32)lv, (u32)i);
  }
  if (istie) {
    u64 tb = (lv == 0) ? t0 : (lv == 1) ? t1 : (lv == 2) ? t2 : t3;
    u32 pre = 0;
    for (int w = 0; w < wid; ++w) pre += wtieS[w][lv];
    u32 pos = tiebase[lv] + pre + (u32)__popcll(tb & lm);
    if (pos < (u32)TIE_CAP) tie[lv * TIE_CAP + pos] = makekey(b, (u32)lv, (u32)i);
  }
}

// 4) bin-P resolution: sort bin members by total-order key, take first RANK
__global__ void k_ties(u32* __restrict__ ctrl, u64* __restrict__ cand,
                       const u64* __restrict__ tie) {
  int lvl = blockIdx.x;
  int tid = threadIdx.x;
  if (ctrl[C_P + lvl] == 0xFFFFFFFFu) return;   // deficient (uniform per block)
  u32 need = ctrl[C_RANK + lvl];
  if (need == 0) return;
  u32 n = min(ctrl[C_TIECNT + lvl], (u32)TIE_CAP);
  u32 m = 2; while (m < n) m <<= 1;
  __shared__ u64 buf[TIE_CAP];
  for (u32 t = tid; t < m; t += 256)
    buf[t] = (t < n) ? tie[lvl * TIE_CAP + t] : ~0ull;
  __syncthreads();
  for (u32 k = 2; k <= m; k <<= 1) {
    for (u32 j = k >> 1; j > 0; j >>= 1) {
      for (u32 p = tid; p < m; p += 256) {
        u32 q = p ^ j;
        if (q > p) {
          u64 a = buf[p], b = buf[q];
          bool desc = (p & k) != 0;
          if (desc ? (a < b) : (a > b)) { buf[p] = b; buf[q] = a; }
        }
      }
      __syncthreads();
    }
  }
  u32 cnt = min(need, n);
  __shared__ u32 basep;
  if (tid == 0) basep = atomicAdd(&ctrl[C_CANDCNT], cnt);
  __syncthreads();
  for (u32 t = tid; t < cnt; t += 256) {
    if (basep + t < (u32)KPAD) cand[basep + t] = buf[t];
  }
}

// 5a) partial enumeration rank (grid 32x8 = all CUs busy) + sepmax fold-in.
//     Each (g,h) block STORES its partial count into rank_part[h][gid]
//     (no atomics, no pre-zeroed buffer).
__global__ __launch_bounds__(256) void k_rankp(const u64* __restrict__ cand,
                                               const u32* __restrict__ ctrl,
                                               const float4* __restrict__ rois,
                                               u32* __restrict__ rank_part,
                                               u32* __restrict__ ctrlw) {
  __shared__ u64 tilek[256];
  int tid = threadIdx.x;
  u32 g = blockIdx.x, h = blockIdx.y;
  u32 total = min(ctrl[C_CANDCNT], (u32)KPAD);
  u32 gid = g * 256 + (u32)tid;
  u64 mykey = (gid < total) ? cand[gid] : ~0ull;
  if (h == 0) {   // sepmax over selected candidates (exact set)
    u32 mx = 0;
    if (gid < total) {
      u32 idx = (u32)(mykey & 0x3FFFFu);
      float4 r = rois[idx];
      mx = max(max(fmap(r.x), fmap(r.y)), max(fmap(r.z), fmap(r.w)));
    }
    for (int o = 32; o; o >>= 1) {
      u32 v = (u32)__shfl_xor((int)mx, o);
      mx = max(mx, v);
    }
    if ((tid & 63) == 0 && mx) atomicMax(&ctrlw[C_SEPMAX], mx);
  }
  u32 jbeg = h * 1024;
  if (jbeg >= total) {                        // uniform per block
    rank_part[h * KPAD + gid] = 0;
    return;
  }
  u32 jend = min(jbeg + 1024, total);
  u32 cnt = 0;
  for (u32 base = jbeg; base < jend; base += 256) {
    u32 n = min(256u, jend - base);
    __syncthreads();
    if ((u32)tid < n) tilek[tid] = cand[base + (u32)tid];
    __syncthreads();
    if (n == 256u) {
#pragma unroll 8
      for (u32 j = 0; j < 256u; ++j) cnt += (tilek[j] < mykey) ? 1u : 0u;
    } else {
      for (u32 j = 0; j < n; ++j) cnt += (tilek[j] < mykey) ? 1u : 0u;
    }
  }
  rank_part[h * KPAD + gid] = cnt;
}

// 5b) scatter by rank (sum of 8 partials; unique keys -> exact permutation)
__global__ __launch_bounds__(256) void k_scatter(const u64* __restrict__ cand,
                                                 const u32* __restrict__ rank_part,
                                                 const u32* __restrict__ ctrl,
                                                 const float4* __restrict__ rois,
                                                 u64* __restrict__ cand2,
                                                 float4* __restrict__ shifted) {
  u32 gid = blockIdx.x * 256 + threadIdx.x;
  u32 total = min(ctrl[C_CANDCNT], (u32)KPAD);
  if (gid >= total) return;
  u64 mykey = cand[gid];
  u32 rank = 0;
#pragma unroll
  for (int h = 0; h < 8; ++h) rank += rank_part[h * KPAD + gid];
  cand2[rank] = mykey;
  float sep = __fadd_rn(funmap(ctrl[C_SEPMAX]), 1.0f);
  u32 idx = (u32)(mykey & 0x3FFFFu);
  u32 lvl = (u32)((mykey >> 18) & 3u);
  float4 r = rois[idx];
  float sh = __fmul_rn((float)lvl, sep);
  float4 o;
  o.x = __fadd_rn(r.x, sh);
  o.y = __fadd_rn(r.y, sh);
  o.z = __fadd_rn(r.z, sh);
  o.w = __fadd_rn(r.w, sh);
  shifted[rank] = o;
}

// 6) build column-major suppression mask. Block = 64 lanes, each lane owns 4
//    columns; row boxes + areas staged in LDS once and reused 4x. Branch-free
//    div-free inner loop; diagonal masking applied once per word.
__global__ __launch_bounds__(64) void k_build(const float4* __restrict__ shifted,
                                              u64* __restrict__ maskT2) {
  u32 rb = blockIdx.y;
  u32 cq = blockIdx.x;                 // col chunks cq*4 .. cq*4+3
  if (cq * 4 + 3 < rb) return;         // entirely below diagonal
  int lane = threadIdx.x;
  __shared__ float4 rbox[64];
  __shared__ float rarea[64];
  float4 rv = shifted[rb * 64 + (u32)lane];
  rbox[lane] = rv;
  rarea[lane] = __fmul_rn(__fsub_rn(rv.z, rv.x), __fsub_rn(rv.w, rv.y));
  __syncthreads();
  u32 j0 = cq * 256 + (u32)lane;
  float4 c0 = shifted[j0];
  float4 c1 = shifted[j0 + 64];
  float4 c2 = shifted[j0 + 128];
  float4 c3 = shifted[j0 + 192];
  float a0 = __fmul_rn(__fsub_rn(c0.z, c0.x), __fsub_rn(c0.w, c0.y));
  float a1 = __fmul_rn(__fsub_rn(c1.z, c1.x), __fsub_rn(c1.w, c1.y));
  float a2 = __fmul_rn(__fsub_rn(c2.z, c2.x), __fsub_rn(c2.w, c2.y));
  float a3 = __fmul_rn(__fsub_rn(c3.z, c3.x), __fsub_rn(c3.w, c3.y));
  u64 b0 = 0, b1 = 0, b2 = 0, b3 = 0;
#pragma unroll 8
  for (int s = 0; s < 64; ++s) {
    float4 r = rbox[s];
    float ra = rarea[s];
    b0 |= (u64)sup_fast(ra, r, a0, c0) << s;
    b1 |= (u64)sup_fast(ra, r, a1, c1) << s;
    b2 |= (u64)sup_fast(ra, r, a2, c2) << s;
    b3 |= (u64)sup_fast(ra, r, a3, c3) << s;
  }
  u64 diagm = (1ull << lane) - 1ull;   // keep rows s with rb*64+s < j (s < lane)
  u32 cb = cq * 4;
  u64* dst = maskT2 + (u64)rb * KPAD + (u64)cb * 64 + (u64)lane;
  if (cb >= rb)     dst[0]   = (cb == rb)     ? (b0 & diagm) : b0;
  if (cb + 1 >= rb) dst[64]  = (cb + 1 == rb) ? (b1 & diagm) : b1;
  if (cb + 2 >= rb) dst[128] = (cb + 2 == rb) ? (b2 & diagm) : b2;
  if (cb + 3 >= rb) dst[192] = (cb + 3 == rb) ? (b3 & diagm) : b3;
}

// 7) pipelined 8-wave greedy scan (unchanged from R11)
__global__ __launch_bounds__(512) void k_scan(const u64* __restrict__ maskT2,
                                              const u64* __restrict__ cand2,
                                              u32* __restrict__ ctrl,
                                              const float2* __restrict__ logits,
                                              const float4* __restrict__ rois,
                                              float* __restrict__ out) {
  __shared__ u64 keptm[NCHUNK];
  __shared__ u64 pre[2][8];
  __shared__ u32 lkept[NPOST];
  __shared__ u32 keptS;
  int tid = threadIdx.x;
  int lane = tid & 63, w = tid >> 6;
  u32 total = min(ctrl[C_CANDCNT], (u32)KPAD);
  u32 chunks = (total + 63) >> 6;
  for (int p = tid; p < NCHUNK; p += 512) keptm[p] = 0;
  if (tid < 8)  pre[0][tid] = 0;
  if (tid >= 8 && tid < 16) pre[1][tid - 8] = 0;
  if (tid == 0) keptS = 0;
  __syncthreads();
  u32 kept = 0;
  u64 keepPrev = 0, lastWord = 0, diagCur = 0;
  if (w == 0 && chunks > 0) diagCur = maskT2[(u64)lane];   // diag word chunk 0
  for (u32 c = 0; c < chunks; ++c) {
    if (w == 0) {
      u64 nDiag = 0, nLast = 0;
      if (c + 1 < chunks) {
        nDiag = maskT2[(u64)(c + 1) * KPAD + (u64)(c + 1) * 64 + (u64)lane];
        nLast = maskT2[(u64)c * KPAD + (u64)(c + 1) * 64 + (u64)lane];
      }
      u64 remc = pre[c & 1][1] | pre[c & 1][2] | pre[c & 1][3] | pre[c & 1][4] |
                 pre[c & 1][5] | pre[c & 1][6] | pre[c & 1][7];
      remc |= __ballot((lastWord & keepPrev) != 0ull);   // ci = c-1 patch
      u64 wv = ~remc;
      u32 rem2 = total - c * 64;
      if (rem2 < 64) wv &= ((1ull << rem2) - 1ull);
      u64 keep = wv;
      for (int it = 0; it < 64; ++it) {
        bool sup = (diagCur & keep) != 0ull;
        u64 nk = wv & ~__ballot(sup);
        if (nk == keep) break;     // uniform within wave
        keep = nk;
      }
      u32 pos = kept + (u32)__popcll(keep & ((1ull << lane) - 1ull));
      if (((keep >> lane) & 1ull) && pos < NPOST) lkept[pos] = c * 64 + (u32)lane;
      if (lane == 0) { keptm[c] = keep; keptS = kept + (u32)__popcll(keep); }
      keepPrev = keep;
      lastWord = nLast;
      diagCur = nDiag;
    } else {
      u64 a0 = 0, a1 = 0;
      if (c + 1 < chunks) {
        const u64* colbase = maskT2 + (u64)(c + 1) * 64 + (u64)lane;
        u32 ci = (u32)(w - 1);
        for (; ci + 7 < c; ci += 14) {
          u64 x0 = colbase[(u64)ci * KPAD] & keptm[ci];
          u64 x1 = colbase[(u64)(ci + 7) * KPAD] & keptm[ci + 7];
          a0 |= x0; a1 |= x1;
        }
        for (; ci < c; ci += 7) a0 |= colbase[(u64)ci * KPAD] & keptm[ci];
      }
      u64 bal = __ballot((a0 | a1) != 0ull);
      if (lane == 0) pre[(c + 1) & 1][w] = bal;
    }
    __syncthreads();
    kept = keptS;
    if (kept >= NPOST) break;
  }
  if (tid == 0) ctrl[C_KEPTCNT] = min(kept, (u32)NPOST);
  __syncthreads();
  u32 kn = min(kept, (u32)NPOST);
  for (u32 r = (u32)tid; r < NPOST; r += 512) {
    float l0 = 0.f, l1 = 0.f, b0 = 0.f, b1 = 0.f, b2 = 0.f, b3 = 0.f;
    float lvf = -1.0f, vf = 0.0f;
    if (r < kn) {
      u32 pos = lkept[r];
      u64 a = cand2[pos];
      u32 idx = (u32)(a & 0x3FFFFu);
      u32 lvl = (u32)((a >> 18) & 3u);
      float4 rb = rois[idx];
      float hs = __fsub_rn(rb.z, rb.x);
      float wsz = __fsub_rn(rb.w, rb.y);
      if (hs >= 1.0f && wsz >= 1.0f) {
        float2 lg = logits[idx];
        l0 = lg.x; l1 = lg.y;
        b0 = rb.x; b1 = rb.y; b2 = rb.z; b3 = rb.w;
        lvf = (float)lvl; vf = 1.0f;
      }
    }
    out[2 * r] = l0;
    out[2 * r + 1] = l1;
    out[2 * NPOST + 4 * r + 0] = b0;
    out[2 * NPOST + 4 * r + 1] = b1;
    out[2 * NPOST + 4 * r + 2] = b2;
    out[2 * NPOST + 4 * r + 3] = b3;
    out[6 * NPOST + r] = lvf;
    out[7 * NPOST + r] = vf;
  }
}

// fallback) sequential greedy NMS (only if ws too small for the mask)
__global__ __launch_bounds__(1024) void k_nms(const float4* __restrict__ shifted,
                                              u32* __restrict__ ctrl, u32* __restrict__ keptpos) {
  __shared__ float4 kbox[NPOST];
  __shared__ u32 wflag[16];
  int tid = threadIdx.x;
  u32 total = min(ctrl[C_CANDCNT], (u32)KPAD);
  int n = 0;
  for (u32 i = 0; i < total; ++i) {
    float4 cur = shifted[i];
    bool sup = false;
    if (tid < n) sup = suppress(kbox[tid], cur);
    int any = __any(sup);
    if ((tid & 63) == 0) wflag[tid >> 6] = (u32)any;
    __syncthreads();
    u32 f = 0;
#pragma unroll
    for (int w = 0; w < 16; ++w) f |= wflag[w];
    if (!f) {
      if (tid == 0) { kbox[n] = cur; keptpos[n] = i; }
      ++n;
    }
    __syncthreads();
    if (n >= NPOST) break;
  }
  if (tid == 0) ctrl[C_KEPTCNT] = (u32)n;
}

// fallback output gather
__global__ void k_out(const u64* __restrict__ cand, const u32* __restrict__ keptpos,
                      const u32* __restrict__ ctrl, const float2* __restrict__ logits,
                      const float4* __restrict__ rois, float* __restrict__ out) {
  int r = blockIdx.x * blockDim.x + threadIdx.x;
  if (r >= NPOST) return;
  u32 kn = ctrl[C_KEPTCNT];
  float l0 = 0.f, l1 = 0.f, r0 = 0.f, r1 = 0.f, r2 = 0.f, r3 = 0.f;
  float lvf = -1.0f, vf = 0.0f;
  if (r < (int)kn) {
    u32 pos = keptpos[r];
    u64 a = cand[pos];
    u32 idx = (u32)(a & 0x3FFFFu);
    u32 lvl = (u32)((a >> 18) & 3u);
    float4 rb = rois[idx];
    float hs = __fsub_rn(rb.z, rb.x);
    float wsz = __fsub_rn(rb.w, rb.y);
    if (hs >= 1.0f && wsz >= 1.0f) {
      float2 lg = logits[idx];
      l0 = lg.x; l1 = lg.y;
      r0 = rb.x; r1 = rb.y; r2 = rb.z; r3 = rb.w;
      lvf = (float)lvl; vf = 1.0f;
    }
  }
  out[2 * r] = l0;
  out[2 * r + 1] = l1;
  out[2 * NPOST + 4 * r + 0] = r0;
  out[2 * NPOST + 4 * r + 1] = r1;
  out[2 * NPOST + 4 * r + 2] = r2;
  out[2 * NPOST + 4 * r + 3] = r3;
  out[6 * NPOST + r] = lvf;
  out[7 * NPOST + r] = vf;
}

extern "C" void kernel_launch(void* const* d_in, const int* in_sizes, int n_in,
                              void* d_out, int out_size, void* d_ws, size_t ws_size,
                              hipStream_t stream) {
  const float* logits = (const float*)d_in[0];
  const float* rois = (const float*)d_in[1];
  const int* levels = (const int*)d_in[2];
  int N = in_sizes[2];

  char* ws = (char*)d_ws;
  u32* sbits = (u32*)(ws + OFF_SBITS);
  u32* ctrl = (u32*)(ws + OFF_CTRL);
  u32* hist1 = (u32*)(ws + OFF_H1);
  u32* histm = (u32*)(ws + OFF_HM);
  u32* rank_part = (u32*)(ws + OFF_RANKP);
  u32* keptpos = (u32*)(ws + OFF_KEPT);
  u64* tie = (u64*)(ws + OFF_TIE);
  u64* cand = (u64*)(ws + OFF_CAND);
  float4* shifted = (float4*)(ws + OFF_SHIFT);
  u64* cand2 = (u64*)(ws + OFF_CAND2);
  u64* maskT2 = (u64*)(ws + OFF_MASK);

  k_zero<<<(ZERO_WORDS + 511) / 512, 512, 0, stream>>>(ctrl);

  int nb2 = (N + 511) / 512;
  k_score_hist<<<nb2, 512, 0, stream>>>((const float2*)logits, levels, sbits, hist1, N);
  k_hist_m<<<nb2, 512, 0, stream>>>(sbits, levels, hist1, histm, N);
  k_compact<<<nb2, 512, 0, stream>>>(sbits, levels, hist1, histm, ctrl, cand, tie, N);
  k_ties<<<NLVL, 256, 0, stream>>>(ctrl, cand, tie);
  {
    dim3 g(KPAD / 256, 8);
    k_rankp<<<g, 256, 0, stream>>>(cand, ctrl, (const float4*)rois, rank_part, ctrl);
  }
  k_scatter<<<KPAD / 256, 256, 0, stream>>>(cand, rank_part, ctrl, (const float4*)rois,
                                            cand2, shifted);
  if (ws_size >= WS_NEED) {
    dim3 g(KPAD / 256, KPAD / 64);
    k_build<<<g, 64, 0, stream>>>((const float4*)shifted, maskT2);
    k_scan<<<1, 512, 0, stream>>>(maskT2, cand2, ctrl,
                                  (const float2*)logits, (const float4*)rois, (float*)d_out);
  } else {
    k_nms<<<1, 1024, 0, stream>>>(shifted, ctrl, keptpos);
    k_out<<<(NPOST + 255) / 256, 256, 0, stream>>>(cand2, keptpos, ctrl, (const float2*)logits,
                                                   (const float4*)rois, (float*)d_out);
  }
}

// Round 18
// 110.983 us; speedup vs baseline: 1.0178x; 1.0178x over previous
//
#include <hip/hip_runtime.h>
#include <stdint.h>

typedef uint32_t u32;
typedef uint64_t u64;

#define NLVL 4
#define NPRE 2000
#define NPOST 1000
#define KPAD 8192
#define TIE_CAP 4096
#define NCHUNK 128          // chunk count (125 used, padded to 128)

// ws layout (bytes)
#define OFF_SBITS 0u                        // 1 MB  (250K u32)
#define OFF_CTRL  (2u<<20)                  // 4 KB  [k_zero]
#define OFF_H1    ((2u<<20) + (4u<<10))     // 4 KB  u32[4][256] exponent hist [k_zero]
#define OFF_HM    ((2u<<20) + (8u<<10))     // 4 KB  u32[4][256] mantissa hist [k_zero]
#define ZERO_WORDS 3072                     // 12 KB contiguous from OFF_CTRL
#define OFF_RANKP ((2u<<20) + (16u<<10))    // 256 KB u32[8][8192] partial ranks (no zeroing)
#define OFF_TIE   ((2u<<20) + (288u<<10))   // 128 KB u64[4][4096]
#define OFF_CAND  ((2u<<20) + (416u<<10))   // 64 KB u64[8192]  (unsorted)
#define OFF_SHIFT ((2u<<20) + (480u<<10))   // 128 KB float4[8192] (sorted order)
#define OFF_CAND2 ((2u<<20) + (608u<<10))   // 64 KB u64[8192]  (sorted)
#define OFF_KEPT  ((2u<<20) + (672u<<10))   // 4 KB  (fallback path only)
#define OFF_MASK  (3u<<20)                  // 8 MB: maskT2[128 row-chunks][8192 cols] u64
#define WS_NEED   ((size_t)(3u<<20) + (size_t)NCHUNK * KPAD * 8u)

// ctrl word indices -- each hot group on its OWN 64B cacheline
#define C_CANDCNT 0    // line 0: block-aggregated adds
#define C_KEPTCNT 1
#define C_SEPMAX  16   // line 1: wave-reduced atomicMax (k_rankp h==0 only)
#define C_P       32   // line 2: threshold (b>>15 value) + RANK (written by k_compact blk0)
#define C_RANK    36
#define C_TIECNT  48   // line 3: block-aggregated tie adds

// exact midpoint between 0.7f (0x3F333333) and nextafterf(0.7f) (0x3F333334):
// RN32(inter/den) > 0.7f  <=>  inter/den >= MID (ties round to even = 0x3F333334 > 0.7f).
// (double)inter and (double)den are exact; MID*(double)den needs <=49 bits -> exact.
#define MID 0x1.666667p-1

// ---- monotone float<->u32 map for atomic max over floats ----
__device__ __forceinline__ u32 fmap(float f) {
  u32 u = __float_as_uint(f);
  return (u & 0x80000000u) ? ~u : (u | 0x80000000u);
}
__device__ __forceinline__ float funmap(u32 u) {
  u = (u & 0x80000000u) ? (u & 0x7FFFFFFFu) : ~u;
  return __uint_as_float(u);
}

// ---- replicate XLA-CPU GenerateVF32Exp (Cephes/Eigen-3.3 style) ----
__device__ __forceinline__ float xla_expf(float x) {
  const float kLog2e = 1.44269504088896341f;
  const float kC1 = 0.693359375f;
  const float kC2 = -2.12194440e-4f;
  const float kP0 = 1.9875691500e-4f;
  const float kP1 = 1.3981999507e-3f;
  const float kP2 = 8.3334519073e-3f;
  const float kP3 = 4.1665795894e-2f;
  const float kP4 = 1.6666665459e-1f;
  const float kP5 = 5.0000001201e-1f;
  float xc = fminf(fmaxf(x, -88.3762626647949f), 88.3762626647950f);
  float fx = floorf(fmaf(xc, kLog2e, 0.5f));
  float tmp = __fmul_rn(kC1, fx);
  float z = __fmul_rn(kC2, fx);
  float r = __fsub_rn(xc, tmp);
  r = __fsub_rn(r, z);
  float r2 = __fmul_rn(r, r);
  float y = fmaf(r, kP0, kP1);
  y = fmaf(y, r, kP2);
  y = fmaf(y, r, kP3);
  y = fmaf(y, r, kP4);
  y = fmaf(y, r, kP5);
  y = fmaf(y, r2, r);
  y = __fadd_rn(y, 1.0f);
  int n = (int)fx;
  float two_n = __int_as_float((n + 127) << 23);
  return fmaxf(__fmul_rn(y, two_n), x);
}

// ---- IoU(a,b) > 0.7f, reference's exact f32 op sequence (fallback path) ----
__device__ __forceinline__ bool suppress(float4 a, float4 b) {
  float aa = __fmul_rn(__fsub_rn(a.z, a.x), __fsub_rn(a.w, a.y));
  float ab = __fmul_rn(__fsub_rn(b.z, b.x), __fsub_rn(b.w, b.y));
  float lty = fmaxf(a.x, b.x);
  float ltx = fmaxf(a.y, b.y);
  float rby = fminf(a.z, b.z);
  float rbx = fminf(a.w, b.w);
  float why = fmaxf(__fsub_rn(rby, lty), 0.0f);
  float whx = fmaxf(__fsub_rn(rbx, ltx), 0.0f);
  float inter = __fmul_rn(why, whx);
  float uni = __fsub_rn(__fadd_rn(aa, ab), inter);
  float iou = inter / fmaxf(uni, 1e-9f);
  return iou > 0.7f;
}

// ---- div-free IoU decision: provably identical to suppress() (see MID note) ----
__device__ __forceinline__ bool sup_fast(float ra, float4 r, float ca, float4 c) {
  float lty = fmaxf(r.x, c.x);
  float ltx = fmaxf(r.y, c.y);
  float rby = fminf(r.z, c.z);
  float rbx = fminf(r.w, c.w);
  float why = fmaxf(__fsub_rn(rby, lty), 0.0f);
  float whx = fmaxf(__fsub_rn(rbx, ltx), 0.0f);
  float inter = __fmul_rn(why, whx);
  float uni = __fsub_rn(__fadd_rn(ra, ca), inter);
  float den = fmaxf(uni, 1e-9f);
  return (double)inter >= MID * (double)den;
}

__device__ __forceinline__ u64 makekey(u32 sbits, u32 lvl, u32 idx) {
  // ascending key == (score desc, level asc, index asc); total order (idx unique)
  return ((u64)(0x7FFFFFFFu - sbits) << 20) | ((u64)lvl << 18) | (u64)idx;
}

// ---- wave-parallel descending rank-scan over a 256-bin histogram ----
__device__ __forceinline__ void rank_scan256(const u32* __restrict__ h, u32 target,
                                             int lane, u32* bin_out, u32* before_out) {
  u32 b0 = h[255 - 4 * lane];
  u32 b1 = h[254 - 4 * lane];
  u32 b2 = h[253 - 4 * lane];
  u32 b3 = h[252 - 4 * lane];
  u32 s = b0 + b1 + b2 + b3;
  u32 inc = s;
  for (int o = 1; o < 64; o <<= 1) {
    u32 v = (u32)__shfl_up((int)inc, o);
    if (lane >= o) inc += v;
  }
  u32 excl = inc - s;
  u32 tot = (u32)__shfl((int)inc, 63);
  if (tot < target) { *bin_out = 0xFFFFFFFFu; *before_out = 0u; return; }
  bool hit = (excl < target) && (excl + s >= target);
  u32 E = 0, before = 0;
  if (hit) {
    u32 cum = excl;
    if (cum + b0 >= target) { E = 255 - 4 * (u32)lane; before = cum; }
    else { cum += b0;
      if (cum + b1 >= target) { E = 254 - 4 * (u32)lane; before = cum; }
      else { cum += b1;
        if (cum + b2 >= target) { E = 253 - 4 * (u32)lane; before = cum; }
        else { cum += b2; E = 252 - 4 * (u32)lane; before = cum; }
      }
    }
  }
  u64 hb = __ballot(hit);
  int src = __ffsll((unsigned long long)hb) - 1;
  *bin_out = (u32)__shfl((int)E, src);
  *before_out = (u32)__shfl((int)before, src);
}

// 0) tiny zero kernel: ctrl + hist1 + histm (12KB)
__global__ __launch_bounds__(512) void k_zero(u32* __restrict__ p) {
  int i = blockIdx.x * 512 + threadIdx.x;
  if (i < ZERO_WORDS) p[i] = 0;
}

// 1) softmax score + LDS-aggregated exponent histogram (4KB global footprint)
__global__ __launch_bounds__(512) void k_score_hist(const float2* __restrict__ logits,
                                                    const int* __restrict__ levels,
                                                    u32* __restrict__ sbits,
                                                    u32* __restrict__ hist1, int n) {
  __shared__ u32 lh[NLVL * 256];
  int tid = threadIdx.x;
  for (int p = tid; p < NLVL * 256; p += 512) lh[p] = 0;
  __syncthreads();
  int i = blockIdx.x * 512 + tid;
  if (i < n) {
    float2 lg = logits[i];
    float m = fmaxf(lg.x, lg.y);
    float e0 = xla_expf(__fsub_rn(lg.x, m));
    float e1 = xla_expf(__fsub_rn(lg.y, m));
    float s = e1 / __fadd_rn(e0, e1);   // IEEE div
    u32 b = __float_as_uint(s);
    sbits[i] = b;
    int lv = levels[i];
    atomicAdd(&lh[lv * 256 + (int)((b >> 23) & 0xFFu)], 1u);
  }
  __syncthreads();
  for (int p = tid; p < NLVL * 256; p += 512) {
    u32 v = lh[p];
    if (v) atomicAdd(&hist1[p], v);
  }
}

// 2) mantissa histogram (bits 22:15) restricted to exp==E; E computed IN-BLOCK
__global__ __launch_bounds__(512) void k_hist_m(const u32* __restrict__ sbits,
                                                const int* __restrict__ levels,
                                                const u32* __restrict__ hist1,
                                                u32* __restrict__ histm, int n) {
  __shared__ u32 lh[NLVL * 256];
  __shared__ u32 sE[NLVL];
  int tid = threadIdx.x;
  int lane = tid & 63, w = tid >> 6;
  for (int p = tid; p < NLVL * 256; p += 512) lh[p] = 0;
  if (w < NLVL) {
    u32 E, bef;
    rank_scan256(hist1 + w * 256, NPRE, lane, &E, &bef);
    if (lane == 0) sE[w] = E;
  }
  __syncthreads();
  int i = blockIdx.x * 512 + tid;
  if (i < n) {
    u32 b = sbits[i];
    int lv = levels[i];
    if (((b >> 23) & 0xFFu) == sE[lv])
      atomicAdd(&lh[lv * 256 + (int)((b >> 15) & 0xFFu)], 1u);
  }
  __syncthreads();
  for (int p = tid; p < NLVL * 256; p += 512) {
    u32 v = lh[p];
    if (v) atomicAdd(&histm[p], v);
  }
}

// 3) compact with BLOCK-AGGREGATED atomics; threshold computed IN-BLOCK.
__global__ __launch_bounds__(512) void k_compact(const u32* __restrict__ sbits,
                                                 const int* __restrict__ levels,
                                                 const u32* __restrict__ hist1,
                                                 const u32* __restrict__ histm,
                                                 u32* __restrict__ ctrl,
                                                 u64* __restrict__ cand,
                                                 u64* __restrict__ tie, int n) {
  __shared__ u32 wcnt[8], wtieS[8][4];
  __shared__ u32 wbase, tiebase[4];
  __shared__ u32 sP[NLVL], sRANK[NLVL];
  int tid = threadIdx.x;
  int wid = tid >> 6, lane = tid & 63;
  if (wid < NLVL) {
    u32 E, bef1;
    rank_scan256(hist1 + wid * 256, NPRE, lane, &E, &bef1);
    u32 P = 0xFFFFFFFFu, RK = 0;
    if (E != 0xFFFFFFFFu) {
      u32 R1 = NPRE - bef1;          // elements needed inside exponent bin E
      u32 M, bef2;
      rank_scan256(histm + wid * 256, R1, lane, &M, &bef2);
      P = (E << 8) | M;
      RK = R1 - bef2;                // elements needed inside threshold bin
    }
    if (lane == 0) {
      sP[wid] = P; sRANK[wid] = RK;
      if (blockIdx.x == 0) { ctrl[C_P + wid] = P; ctrl[C_RANK + wid] = RK; }
    }
  }
  __syncthreads();
  int i = blockIdx.x * 512 + tid;
  bool act = i < n;
  u32 b = 0; int lv = 0; u32 P = 0xFFFFFFFEu;
  if (act) {
    b = sbits[i];
    lv = levels[i];
    P = sP[lv];
  }
  u32 K = b >> 15;
  bool iscand = act && (P == 0xFFFFFFFFu || K > P);
  bool istie  = act && !iscand && (K == P);
  u64 cb = __ballot(iscand);
  u64 t0 = __ballot(istie && lv == 0);
  u64 t1 = __ballot(istie && lv == 1);
  u64 t2 = __ballot(istie && lv == 2);
  u64 t3 = __ballot(istie && lv == 3);
  if (lane == 0) {
    wcnt[wid] = (u32)__popcll(cb);
    wtieS[wid][0] = (u32)__popcll(t0);
    wtieS[wid][1] = (u32)__popcll(t1);
    wtieS[wid][2] = (u32)__popcll(t2);
    wtieS[wid][3] = (u32)__popcll(t3);
  }
  __syncthreads();
  if (tid == 0) {
    u32 tot = 0;
#pragma unroll
    for (int w = 0; w < 8; ++w) tot += wcnt[w];
    wbase = tot ? atomicAdd(&ctrl[C_CANDCNT], tot) : 0u;
  }
  if (tid < 4) {
    u32 tt = 0;
#pragma unroll
    for (int w = 0; w < 8; ++w) tt += wtieS[w][tid];
    tiebase[tid] = tt ? atomicAdd(&ctrl[C_TIECNT + tid], tt) : 0u;
  }
  __syncthreads();
  u64 lm = (1ull << lane) - 1ull;
  if (iscand) {
    u32 pre = 0;
    for (int w = 0; w < wid; ++w) pre += wcnt[w];
    u32 pos = wbase + pre + (u32)__popcll(cb & lm);
    if (pos < (u32)KPAD) cand[pos] = makekey(b, (u32)lv, (u32)i);
  }
  if (istie) {
    u64 tb = (lv == 0) ? t0 : (lv == 1) ? t1 : (lv == 2) ? t2 : t3;
    u32 pre = 0;
    for (int w = 0; w < wid; ++w) pre += wtieS[w][lv];
    u32 pos = tiebase[lv] + pre + (u32)__popcll(tb & lm);
    if (pos < (u32)TIE_CAP) tie[lv * TIE_CAP + pos] = makekey(b, (u32)lv, (u32)i);
  }
}

// 4) bin-P resolution: sort bin members by total-order key, take first RANK
__global__ void k_ties(u32* __restrict__ ctrl, u64* __restrict__ cand,
                       const u64* __restrict__ tie) {
  int lvl = blockIdx.x;
  int tid = threadIdx.x;
  if (ctrl[C_P + lvl] == 0xFFFFFFFFu) return;   // deficient (uniform per block)
  u32 need = ctrl[C_RANK + lvl];
  if (need == 0) return;
  u32 n = min(ctrl[C_TIECNT + lvl], (u32)TIE_CAP);
  u32 m = 2; while (m < n) m <<= 1;
  __shared__ u64 buf[TIE_CAP];
  for (u32 t = tid; t < m; t += 256)
    buf[t] = (t < n) ? tie[lvl * TIE_CAP + t] : ~0ull;
  __syncthreads();
  for (u32 k = 2; k <= m; k <<= 1) {
    for (u32 j = k >> 1; j > 0; j >>= 1) {
      for (u32 p = tid; p < m; p += 256) {
        u32 q = p ^ j;
        if (q > p) {
          u64 a = buf[p], b = buf[q];
          bool desc = (p & k) != 0;
          if (desc ? (a < b) : (a > b)) { buf[p] = b; buf[q] = a; }
        }
      }
      __syncthreads();
    }
  }
  u32 cnt = min(need, n);
  __shared__ u32 basep;
  if (tid == 0) basep = atomicAdd(&ctrl[C_CANDCNT], cnt);
  __syncthreads();
  for (u32 t = tid; t < cnt; t += 256) {
    if (basep + t < (u32)KPAD) cand[basep + t] = buf[t];
  }
}

// 5a) partial enumeration rank (grid 32x8 = all CUs busy) + sepmax fold-in.
__global__ __launch_bounds__(256) void k_rankp(const u64* __restrict__ cand,
                                               const u32* __restrict__ ctrl,
                                               const float4* __restrict__ rois,
                                               u32* __restrict__ rank_part,
                                               u32* __restrict__ ctrlw) {
  __shared__ u64 tilek[256];
  int tid = threadIdx.x;
  u32 g = blockIdx.x, h = blockIdx.y;
  u32 total = min(ctrl[C_CANDCNT], (u32)KPAD);
  u32 gid = g * 256 + (u32)tid;
  u64 mykey = (gid < total) ? cand[gid] : ~0ull;
  if (h == 0) {   // sepmax over selected candidates (exact set)
    u32 mx = 0;
    if (gid < total) {
      u32 idx = (u32)(mykey & 0x3FFFFu);
      float4 r = rois[idx];
      mx = max(max(fmap(r.x), fmap(r.y)), max(fmap(r.z), fmap(r.w)));
    }
    for (int o = 32; o; o >>= 1) {
      u32 v = (u32)__shfl_xor((int)mx, o);
      mx = max(mx, v);
    }
    if ((tid & 63) == 0 && mx) atomicMax(&ctrlw[C_SEPMAX], mx);
  }
  u32 jbeg = h * 1024;
  if (jbeg >= total) {                        // uniform per block
    rank_part[h * KPAD + gid] = 0;
    return;
  }
  u32 jend = min(jbeg + 1024, total);
  u32 cnt = 0;
  for (u32 base = jbeg; base < jend; base += 256) {
    u32 n = min(256u, jend - base);
    __syncthreads();
    if ((u32)tid < n) tilek[tid] = cand[base + (u32)tid];
    __syncthreads();
    if (n == 256u) {
#pragma unroll 8
      for (u32 j = 0; j < 256u; ++j) cnt += (tilek[j] < mykey) ? 1u : 0u;
    } else {
      for (u32 j = 0; j < n; ++j) cnt += (tilek[j] < mykey) ? 1u : 0u;
    }
  }
  rank_part[h * KPAD + gid] = cnt;
}

// 5b) scatter by rank (sum of 8 partials; unique keys -> exact permutation)
__global__ __launch_bounds__(256) void k_scatter(const u64* __restrict__ cand,
                                                 const u32* __restrict__ rank_part,
                                                 const u32* __restrict__ ctrl,
                                                 const float4* __restrict__ rois,
                                                 u64* __restrict__ cand2,
                                                 float4* __restrict__ shifted) {
  u32 gid = blockIdx.x * 256 + threadIdx.x;
  u32 total = min(ctrl[C_CANDCNT], (u32)KPAD);
  if (gid >= total) return;
  u64 mykey = cand[gid];
  u32 rank = 0;
#pragma unroll
  for (int h = 0; h < 8; ++h) rank += rank_part[h * KPAD + gid];
  cand2[rank] = mykey;
  float sep = __fadd_rn(funmap(ctrl[C_SEPMAX]), 1.0f);
  u32 idx = (u32)(mykey & 0x3FFFFu);
  u32 lvl = (u32)((mykey >> 18) & 3u);
  float4 r = rois[idx];
  float sh = __fmul_rn((float)lvl, sep);
  float4 o;
  o.x = __fadd_rn(r.x, sh);
  o.y = __fadd_rn(r.y, sh);
  o.z = __fadd_rn(r.z, sh);
  o.w = __fadd_rn(r.w, sh);
  shifted[rank] = o;
}

// 6) build column-major suppression mask. Block = 256 threads (4 waves); wave w
//    owns col-chunks cs*16+4w..+3, each lane 4 columns. Row boxes + areas staged
//    in LDS ONCE per block and shared by all 4 waves. Branch-free div-free
//    inner loop; diagonal masking applied once per word.
__global__ __launch_bounds__(256) void k_build(const float4* __restrict__ shifted,
                                               u64* __restrict__ maskT2) {
  u32 rb = blockIdx.y;
  u32 cs = blockIdx.x;                 // 1024-column super-chunk
  if (cs * 16 + 15 < rb) return;       // entirely below diagonal (uniform)
  int tid = threadIdx.x;
  int lane = tid & 63, w = tid >> 6;
  __shared__ float4 rbox[64];
  __shared__ float rarea[64];
  if (tid < 64) {
    float4 rv = shifted[rb * 64 + (u32)tid];
    rbox[tid] = rv;
    rarea[tid] = __fmul_rn(__fsub_rn(rv.z, rv.x), __fsub_rn(rv.w, rv.y));
  }
  __syncthreads();
  u32 cb0 = cs * 16 + (u32)w * 4;      // this wave's first col-chunk
  if (cb0 + 3 < rb) return;            // wave entirely below diagonal (no more barriers)
  u32 j0 = cb0 * 64 + (u32)lane;
  float4 c0 = shifted[j0];
  float4 c1 = shifted[j0 + 64];
  float4 c2 = shifted[j0 + 128];
  float4 c3 = shifted[j0 + 192];
  float a0 = __fmul_rn(__fsub_rn(c0.z, c0.x), __fsub_rn(c0.w, c0.y));
  float a1 = __fmul_rn(__fsub_rn(c1.z, c1.x), __fsub_rn(c1.w, c1.y));
  float a2 = __fmul_rn(__fsub_rn(c2.z, c2.x), __fsub_rn(c2.w, c2.y));
  float a3 = __fmul_rn(__fsub_rn(c3.z, c3.x), __fsub_rn(c3.w, c3.y));
  u64 b0 = 0, b1 = 0, b2 = 0, b3 = 0;
#pragma unroll 8
  for (int s = 0; s < 64; ++s) {
    float4 r = rbox[s];
    float ra = rarea[s];
    b0 |= (u64)sup_fast(ra, r, a0, c0) << s;
    b1 |= (u64)sup_fast(ra, r, a1, c1) << s;
    b2 |= (u64)sup_fast(ra, r, a2, c2) << s;
    b3 |= (u64)sup_fast(ra, r, a3, c3) << s;
  }
  u64 diagm = (1ull << lane) - 1ull;   // keep rows s with rb*64+s < j (s < lane)
  u64* dst = maskT2 + (u64)rb * KPAD + (u64)cb0 * 64 + (u64)lane;
  if (cb0 >= rb)     dst[0]   = (cb0 == rb)     ? (b0 & diagm) : b0;
  if (cb0 + 1 >= rb) dst[64]  = (cb0 + 1 == rb) ? (b1 & diagm) : b1;
  if (cb0 + 2 >= rb) dst[128] = (cb0 + 2 == rb) ? (b2 & diagm) : b2;
  if (cb0 + 3 >= rb) dst[192] = (cb0 + 3 == rb) ? (b3 & diagm) : b3;
}

// 7) pipelined 8-wave greedy scan (unchanged)
__global__ __launch_bounds__(512) void k_scan(const u64* __restrict__ maskT2,
                                              const u64* __restrict__ cand2,
                                              u32* __restrict__ ctrl,
                                              const float2* __restrict__ logits,
                                              const float4* __restrict__ rois,
                                              float* __restrict__ out) {
  __shared__ u64 keptm[NCHUNK];
  __shared__ u64 pre[2][8];
  __shared__ u32 lkept[NPOST];
  __shared__ u32 keptS;
  int tid = threadIdx.x;
  int lane = tid & 63, w = tid >> 6;
  u32 total = min(ctrl[C_CANDCNT], (u32)KPAD);
  u32 chunks = (total + 63) >> 6;
  for (int p = tid; p < NCHUNK; p += 512) keptm[p] = 0;
  if (tid < 8)  pre[0][tid] = 0;
  if (tid >= 8 && tid < 16) pre[1][tid - 8] = 0;
  if (tid == 0) keptS = 0;
  __syncthreads();
  u32 kept = 0;
  u64 keepPrev = 0, lastWord = 0, diagCur = 0;
  if (w == 0 && chunks > 0) diagCur = maskT2[(u64)lane];   // diag word chunk 0
  for (u32 c = 0; c < chunks; ++c) {
    if (w == 0) {
      u64 nDiag = 0, nLast = 0;
      if (c + 1 < chunks) {
        nDiag = maskT2[(u64)(c + 1) * KPAD + (u64)(c + 1) * 64 + (u64)lane];
        nLast = maskT2[(u64)c * KPAD + (u64)(c + 1) * 64 + (u64)lane];
      }
      u64 remc = pre[c & 1][1] | pre[c & 1][2] | pre[c & 1][3] | pre[c & 1][4] |
                 pre[c & 1][5] | pre[c & 1][6] | pre[c & 1][7];
      remc |= __ballot((lastWord & keepPrev) != 0ull);   // ci = c-1 patch
      u64 wv = ~remc;
      u32 rem2 = total - c * 64;
      if (rem2 < 64) wv &= ((1ull << rem2) - 1ull);
      u64 keep = wv;
      for (int it = 0; it < 64; ++it) {
        bool sup = (diagCur & keep) != 0ull;
        u64 nk = wv & ~__ballot(sup);
        if (nk == keep) break;     // uniform within wave
        keep = nk;
      }
      u32 pos = kept + (u32)__popcll(keep & ((1ull << lane) - 1ull));
      if (((keep >> lane) & 1ull) && pos < NPOST) lkept[pos] = c * 64 + (u32)lane;
      if (lane == 0) { keptm[c] = keep; keptS = kept + (u32)__popcll(keep); }
      keepPrev = keep;
      lastWord = nLast;
      diagCur = nDiag;
    } else {
      u64 a0 = 0, a1 = 0;
      if (c + 1 < chunks) {
        const u64* colbase = maskT2 + (u64)(c + 1) * 64 + (u64)lane;
        u32 ci = (u32)(w - 1);
        for (; ci + 7 < c; ci += 14) {
          u64 x0 = colbase[(u64)ci * KPAD] & keptm[ci];
          u64 x1 = colbase[(u64)(ci + 7) * KPAD] & keptm[ci + 7];
          a0 |= x0; a1 |= x1;
        }
        for (; ci < c; ci += 7) a0 |= colbase[(u64)ci * KPAD] & keptm[ci];
      }
      u64 bal = __ballot((a0 | a1) != 0ull);
      if (lane == 0) pre[(c + 1) & 1][w] = bal;
    }
    __syncthreads();
    kept = keptS;
    if (kept >= NPOST) break;
  }
  if (tid == 0) ctrl[C_KEPTCNT] = min(kept, (u32)NPOST);
  __syncthreads();
  u32 kn = min(kept, (u32)NPOST);
  for (u32 r = (u32)tid; r < NPOST; r += 512) {
    float l0 = 0.f, l1 = 0.f, b0 = 0.f, b1 = 0.f, b2 = 0.f, b3 = 0.f;
    float lvf = -1.0f, vf = 0.0f;
    if (r < kn) {
      u32 pos = lkept[r];
      u64 a = cand2[pos];
      u32 idx = (u32)(a & 0x3FFFFu);
      u32 lvl = (u32)((a >> 18) & 3u);
      float4 rb = rois[idx];
      float hs = __fsub_rn(rb.z, rb.x);
      float wsz = __fsub_rn(rb.w, rb.y);
      if (hs >= 1.0f && wsz >= 1.0f) {
        float2 lg = logits[idx];
        l0 = lg.x; l1 = lg.y;
        b0 = rb.x; b1 = rb.y; b2 = rb.z; b3 = rb.w;
        lvf = (float)lvl; vf = 1.0f;
      }
    }
    out[2 * r] = l0;
    out[2 * r + 1] = l1;
    out[2 * NPOST + 4 * r + 0] = b0;
    out[2 * NPOST + 4 * r + 1] = b1;
    out[2 * NPOST + 4 * r + 2] = b2;
    out[2 * NPOST + 4 * r + 3] = b3;
    out[6 * NPOST + r] = lvf;
    out[7 * NPOST + r] = vf;
  }
}

// fallback) sequential greedy NMS (only if ws too small for the mask)
__global__ __launch_bounds__(1024) void k_nms(const float4* __restrict__ shifted,
                                              u32* __restrict__ ctrl, u32* __restrict__ keptpos) {
  __shared__ float4 kbox[NPOST];
  __shared__ u32 wflag[16];
  int tid = threadIdx.x;
  u32 total = min(ctrl[C_CANDCNT], (u32)KPAD);
  int n = 0;
  for (u32 i = 0; i < total; ++i) {
    float4 cur = shifted[i];
    bool sup = false;
    if (tid < n) sup = suppress(kbox[tid], cur);
    int any = __any(sup);
    if ((tid & 63) == 0) wflag[tid >> 6] = (u32)any;
    __syncthreads();
    u32 f = 0;
#pragma unroll
    for (int w = 0; w < 16; ++w) f |= wflag[w];
    if (!f) {
      if (tid == 0) { kbox[n] = cur; keptpos[n] = i; }
      ++n;
    }
    __syncthreads();
    if (n >= NPOST) break;
  }
  if (tid == 0) ctrl[C_KEPTCNT] = (u32)n;
}

// fallback output gather
__global__ void k_out(const u64* __restrict__ cand, const u32* __restrict__ keptpos,
                      const u32* __restrict__ ctrl, const float2* __restrict__ logits,
                      const float4* __restrict__ rois, float* __restrict__ out) {
  int r = blockIdx.x * blockDim.x + threadIdx.x;
  if (r >= NPOST) return;
  u32 kn = ctrl[C_KEPTCNT];
  float l0 = 0.f, l1 = 0.f, r0 = 0.f, r1 = 0.f, r2 = 0.f, r3 = 0.f;
  float lvf = -1.0f, vf = 0.0f;
  if (r < (int)kn) {
    u32 pos = keptpos[r];
    u64 a = cand[pos];
    u32 idx = (u32)(a & 0x3FFFFu);
    u32 lvl = (u32)((a >> 18) & 3u);
    float4 rb = rois[idx];
    float hs = __fsub_rn(rb.z, rb.x);
    float wsz = __fsub_rn(rb.w, rb.y);
    if (hs >= 1.0f && wsz >= 1.0f) {
      float2 lg = logits[idx];
      l0 = lg.x; l1 = lg.y;
      r0 = rb.x; r1 = rb.y; r2 = rb.z; r3 = rb.w;
      lvf = (float)lvl; vf = 1.0f;
    }
  }
  out[2 * r] = l0;
  out[2 * r + 1] = l1;
  out[2 * NPOST + 4 * r + 0] = r0;
  out[2 * NPOST + 4 * r + 1] = r1;
  out[2 * NPOST + 4 * r + 2] = r2;
  out[2 * NPOST + 4 * r + 3] = r3;
  out[6 * NPOST + r] = lvf;
  out[7 * NPOST + r] = vf;
}

extern "C" void kernel_launch(void* const* d_in, const int* in_sizes, int n_in,
                              void* d_out, int out_size, void* d_ws, size_t ws_size,
                              hipStream_t stream) {
  const float* logits = (const float*)d_in[0];
  const float* rois = (const float*)d_in[1];
  const int* levels = (const int*)d_in[2];
  int N = in_sizes[2];

  char* ws = (char*)d_ws;
  u32* sbits = (u32*)(ws + OFF_SBITS);
  u32* ctrl = (u32*)(ws + OFF_CTRL);
  u32* hist1 = (u32*)(ws + OFF_H1);
  u32* histm = (u32*)(ws + OFF_HM);
  u32* rank_part = (u32*)(ws + OFF_RANKP);
  u32* keptpos = (u32*)(ws + OFF_KEPT);
  u64* tie = (u64*)(ws + OFF_TIE);
  u64* cand = (u64*)(ws + OFF_CAND);
  float4* shifted = (float4*)(ws + OFF_SHIFT);
  u64* cand2 = (u64*)(ws + OFF_CAND2);
  u64* maskT2 = (u64*)(ws + OFF_MASK);

  k_zero<<<(ZERO_WORDS + 511) / 512, 512, 0, stream>>>(ctrl);

  int nb2 = (N + 511) / 512;
  k_score_hist<<<nb2, 512, 0, stream>>>((const float2*)logits, levels, sbits, hist1, N);
  k_hist_m<<<nb2, 512, 0, stream>>>(sbits, levels, hist1, histm, N);
  k_compact<<<nb2, 512, 0, stream>>>(sbits, levels, hist1, histm, ctrl, cand, tie, N);
  k_ties<<<NLVL, 256, 0, stream>>>(ctrl, cand, tie);
  {
    dim3 g(KPAD / 256, 8);
    k_rankp<<<g, 256, 0, stream>>>(cand, ctrl, (const float4*)rois, rank_part, ctrl);
  }
  k_scatter<<<KPAD / 256, 256, 0, stream>>>(cand, rank_part, ctrl, (const float4*)rois,
                                            cand2, shifted);
  if (ws_size >= WS_NEED) {
    dim3 g(KPAD / 1024, KPAD / 64);   // (8, 128): 4-wave blocks, 1024 cols each
    k_build<<<g, 256, 0, stream>>>((const float4*)shifted, maskT2);
    k_scan<<<1, 512, 0, stream>>>(maskT2, cand2, ctrl,
                                  (const float2*)logits, (const float4*)rois, (float*)d_out);
  } else {
    k_nms<<<1, 1024, 0, stream>>>(shifted, ctrl, keptpos);
    k_out<<<(NPOST + 255) / 256, 256, 0, stream>>>(cand2, keptpos, ctrl, (const float2*)logits,
                                                   (const float4*)rois, (float*)d_out);
  }
}